// Round 2
// baseline (274.280 us; speedup 1.0000x reference)
//
#include <hip/hip_runtime.h>
#include <hip/hip_bf16.h>

typedef unsigned short u16;
typedef unsigned int u32;

#define AGT 8
#define NBATCH 32768
#define DDIM 128
#define HEADS 4
#define KDIM 32
#define CC 128        // HEADS*KDIM
#define NT 8
#define MROWS 64      // AGT*NT

typedef float f32x4 __attribute__((ext_vector_type(4)));
typedef float f32x2 __attribute__((ext_vector_type(2)));
typedef __bf16 bf16x8 __attribute__((ext_vector_type(8)));
typedef short s16x8 __attribute__((ext_vector_type(8)));
typedef u32 u32x4 __attribute__((ext_vector_type(4)));

union FragU { s16x8 s; bf16x8 b; u32x4 u; };

__device__ __forceinline__ u16 f2bf(float f) {
  u32 u = __float_as_uint(f);
  u = (u + 0x7FFFu + ((u >> 16) & 1u)) >> 16;
  return (u16)u;
}

// packed f32->bf16 RNE, 2 elems / instr (no builtin on gfx950 — T12 recipe)
__device__ __forceinline__ u32 cvtpk(float lo, float hi) {
  u32 r;
  asm("v_cvt_pk_bf16_f32 %0, %1, %2" : "=v"(r) : "v"(lo), "v"(hi));
  return r;
}

// bf16 pair (packed in u32) -> f32x2, 1 VALU per element
__device__ __forceinline__ f32x2 bfpair(u32 u) {
  f32x2 r;
  r.x = __uint_as_float(u << 16);
  r.y = __uint_as_float(u & 0xFFFF0000u);
  return r;
}

// Rearrange W[h][k][d] (f32) into bf16 MFMA B-fragment order:
// Wb[(((pj*8+ct)*4+kc)*64+l)*8+b] = W_pj[c>>5][c&31][d],
//   c = ct*16 + (l&15),  d = kc*32 + (b>>2)*16 + ((l>>4)<<2) + (b&3)
__global__ void prep_weights(const float* __restrict__ Wk,
                             const float* __restrict__ Ws,
                             const float* __restrict__ Wv,
                             u16* __restrict__ Wb) {
  int idx = blockIdx.x * 256 + threadIdx.x;
  if (idx >= 3 * 8 * 4 * 64 * 8) return;
  int b  = idx & 7;
  int l  = (idx >> 3) & 63;
  int kc = (idx >> 9) & 3;
  int ct = (idx >> 11) & 7;
  int pj = idx >> 14;
  int c = ct * 16 + (l & 15);
  int h = c >> 5, kk = c & 31;
  int d = kc * 32 + ((b >> 2) << 4) + ((l >> 4) << 2) + (b & 3);
  const float* W = (pj == 0) ? Wk : ((pj == 1) ? Ws : Wv);
  Wb[idx] = f2bf(W[(h * KDIM + kk) * DDIM + d]);
}

__global__ __launch_bounds__(256, 3) void fused_attn(
    const float* __restrict__ qin, const float* __restrict__ kin,
    const float* __restrict__ vin, const u16* __restrict__ Wb,
    const float* __restrict__ bv,
    float* __restrict__ out0, float* __restrict__ out1,
    float* __restrict__ out2) {
  // hk / hs / hv as bf16 [64 rows][128 cols], XOR-swizzled:
  // elem(row,c) at byte row*256 + ((c*2) ^ ((row&7)<<4))
  __shared__ __align__(16) u16 sH[3][MROWS * CC];

  const int tid = threadIdx.x;
  const int l = tid & 63;
  const int w = tid >> 6;
  const int n0 = blockIdx.x * NT;
  const int lr = l & 15;
  const int lg = l >> 4;

  // ---- projection phase: each wave owns rows [16w, 16w+16) ----
  const int arow = w * 16 + lr;                 // local row = agent*8 + nt
  const size_t grow_off =
      ((size_t)(arow >> 3) * NBATCH + (size_t)(n0 + (arow & 7))) * DDIM;

  // Load ALL THREE projections' A-fragments up front (one vmcnt drain,
  // maximal load ILP), converting f32->bf16 with packed cvt.
  FragU fa[3][4];
#pragma unroll
  for (int pj = 0; pj < 3; ++pj) {
    const float* X = (pj == 0) ? kin : ((pj == 1) ? qin : vin);
    const float* grow = X + grow_off;
#pragma unroll
    for (int kc = 0; kc < 4; ++kc) {
      const float4 x0 = *(const float4*)(grow + kc * 32 + lg * 4);
      const float4 x1 = *(const float4*)(grow + kc * 32 + lg * 4 + 16);
      u32x4 t;
      t[0] = cvtpk(x0.x, x0.y);
      t[1] = cvtpk(x0.z, x0.w);
      t[2] = cvtpk(x1.x, x1.y);
      t[3] = cvtpk(x1.z, x1.w);
      fa[pj][kc].u = t;
    }
  }

#pragma unroll
  for (int pj = 0; pj < 3; ++pj) {
    f32x4 acc[8];
#pragma unroll
    for (int ct = 0; ct < 8; ++ct) acc[ct] = (f32x4)(0.0f);

#pragma unroll
    for (int ct = 0; ct < 8; ++ct) {
#pragma unroll
      for (int kc = 0; kc < 4; ++kc) {
        FragU fb;
        fb.s = *(const s16x8*)(Wb + ((((pj * 8 + ct) * 4 + kc) * 64 + l) << 3));
        acc[ct] = __builtin_amdgcn_mfma_f32_16x16x32_bf16(fa[pj][kc].b, fb.b,
                                                          acc[ct], 0, 0, 0);
      }
    }

    // epilogue: D-frag lane l holds col=l&15(+16*ct), rows (l>>4)*4 + rg
    u16* dst = sH[pj];
#pragma unroll
    for (int ct = 0; ct < 8; ++ct) {
      const int c = ct * 16 + lr;
      float x[4];
#pragma unroll
      for (int rg = 0; rg < 4; ++rg) x[rg] = acc[ct][rg];
      if (pj == 2) {
        const float bias = bv[c];
#pragma unroll
        for (int rg = 0; rg < 4; ++rg) {
          float v = x[rg] + bias;
          x[rg] = (v > 0.0f) ? v : 0.01f * v;
        }
      }
      const u32 p01 = cvtpk(x[0], x[1]);
      const u32 p23 = cvtpk(x[2], x[3]);
      const int rb = w * 16 + lg * 4;
      const int cb = c * 2;
#pragma unroll
      for (int rg = 0; rg < 4; ++rg) {
        const int row = rb + rg;
        const u32 pk = (rg < 2) ? p01 : p23;
        const u16 val = (rg & 1) ? (u16)(pk >> 16) : (u16)pk;
        *(u16*)((char*)dst + row * 256 + (cb ^ ((row & 7) << 4))) = val;
      }
    }
  }

  __syncthreads();

  // ---- attention phase: thread = (h=wave, i=l>>3, nt=l&7) ----
  const int h = w;
  const int i = l >> 3;
  const int nt = l & 7;
  const int n = n0 + nt;
  const int cb2 = h * 64;  // byte offset of col base h*32

  // own selector row, as 16 packed f32 pairs
  f32x2 hs2[16];
  {
    const int r = i * 8 + nt;
    const int swz = (r & 7) << 4;
#pragma unroll
    for (int qc = 0; qc < 4; ++qc) {
      u32x4 ch = *(const u32x4*)((const char*)sH[1] + r * 256 +
                                 ((cb2 + qc * 16) ^ swz));
#pragma unroll
      for (int e = 0; e < 4; ++e) hs2[qc * 4 + e] = bfpair(ch[e]);
    }
  }

  float logits[8];
#pragma unroll
  for (int j = 0; j < 8; ++j) {
    const int r = j * 8 + nt;
    const int swz = (r & 7) << 4;
    f32x2 a2 = (f32x2)(0.0f);
#pragma unroll
    for (int qc = 0; qc < 4; ++qc) {
      u32x4 ch = *(const u32x4*)((const char*)sH[0] + r * 256 +
                                 ((cb2 + qc * 16) ^ swz));
#pragma unroll
      for (int e = 0; e < 4; ++e) a2 = bfpair(ch[e]) * hs2[qc * 4 + e] + a2;
    }
    logits[j] = a2.x + a2.y;
  }

  const float scale = 0.17677669529663687f;  // 1/sqrt(32)
  float sl[8];
#pragma unroll
  for (int j = 0; j < 8; ++j) sl[j] = (j == i) ? -1e30f : logits[j] * scale;
  float m = sl[0];
#pragma unroll
  for (int j = 1; j < 8; ++j) m = fmaxf(m, sl[j]);
  float p[8];
  float s = 0.0f;
#pragma unroll
  for (int j = 0; j < 8; ++j) { p[j] = __expf(sl[j] - m); s += p[j]; }
  const float inv = 1.0f / s;

  const size_t ob = ((size_t)(i * HEADS + h) * NBATCH + (size_t)n);
  const size_t ob7 = ob * 7;
#pragma unroll
  for (int j = 0; j < 8; ++j) {
    if (j != i) {
      const int jj = j - ((j > i) ? 1 : 0);
      out1[ob7 + jj] = logits[j];      // UNSCALED logits (reference semantics)
      out2[ob7 + jj] = p[j] * inv;
    }
  }

  // PV: packed f32x2 accumulate
  f32x2 o2[16];
#pragma unroll
  for (int e = 0; e < 16; ++e) o2[e] = (f32x2)(0.0f);
#pragma unroll
  for (int j = 0; j < 8; ++j) {
    const float pw = p[j] * inv;       // pw == 0 for j == i
    const f32x2 pw2 = (f32x2)(pw);
    const int r = j * 8 + nt;
    const int swz = (r & 7) << 4;
#pragma unroll
    for (int qc = 0; qc < 4; ++qc) {
      u32x4 ch = *(const u32x4*)((const char*)sH[2] + r * 256 +
                                 ((cb2 + qc * 16) ^ swz));
#pragma unroll
      for (int e = 0; e < 4; ++e)
        o2[qc * 4 + e] = bfpair(ch[e]) * pw2 + o2[qc * 4 + e];
    }
  }

  const size_t o0 = ob * 32;
#pragma unroll
  for (int g = 0; g < 8; ++g) {
    float4 vv = make_float4(o2[g * 2].x, o2[g * 2].y,
                            o2[g * 2 + 1].x, o2[g * 2 + 1].y);
    *(float4*)(out0 + o0 + g * 4) = vv;
  }
}

extern "C" void kernel_launch(void* const* d_in, const int* in_sizes, int n_in,
                              void* d_out, int out_size, void* d_ws,
                              size_t ws_size, hipStream_t stream) {
  const float* qin = (const float*)d_in[0];
  const float* kin = (const float*)d_in[1];
  const float* vin = (const float*)d_in[2];
  const float* Wk  = (const float*)d_in[3];
  const float* Ws  = (const float*)d_in[4];
  const float* Wv  = (const float*)d_in[5];
  const float* bvp = (const float*)d_in[6];

  float* out0 = (float*)d_out;
  float* out1 = out0 + (size_t)AGT * HEADS * NBATCH * KDIM;
  float* out2 = out1 + (size_t)AGT * HEADS * NBATCH * 7;

  u16* Wb = (u16*)d_ws;  // 98304 bytes needed

  prep_weights<<<dim3(192), dim3(256), 0, stream>>>(Wk, Ws, Wv, Wb);
  fused_attn<<<dim3(NBATCH / NT), dim3(256), 0, stream>>>(
      qin, kin, vin, Wb, bvp, out0, out1, out2);
}

// Round 3
// 273.209 us; speedup vs baseline: 1.0039x; 1.0039x over previous
//
#include <hip/hip_runtime.h>
#include <hip/hip_bf16.h>

typedef unsigned short u16;
typedef unsigned int u32;

#define AGT 8
#define NBATCH 32768
#define DDIM 128
#define HEADS 4
#define KDIM 32
#define CC 128        // HEADS*KDIM
#define NT 4
#define MROWS 32      // AGT*NT

typedef float f32x4 __attribute__((ext_vector_type(4)));
typedef float f32x2 __attribute__((ext_vector_type(2)));
typedef __bf16 bf16x8 __attribute__((ext_vector_type(8)));
typedef short s16x8 __attribute__((ext_vector_type(8)));
typedef u32 u32x4 __attribute__((ext_vector_type(4)));

union FragU { s16x8 s; bf16x8 b; u32x4 u; };

__device__ __forceinline__ u16 f2bf(float f) {
  u32 u = __float_as_uint(f);
  u = (u + 0x7FFFu + ((u >> 16) & 1u)) >> 16;
  return (u16)u;
}

// packed f32->bf16 RNE, 2 elems / instr (no builtin on gfx950 — T12 recipe)
__device__ __forceinline__ u32 cvtpk(float lo, float hi) {
  u32 r;
  asm("v_cvt_pk_bf16_f32 %0, %1, %2" : "=v"(r) : "v"(lo), "v"(hi));
  return r;
}

// bf16 pair (packed in u32) -> f32x2, 1 VALU per element
__device__ __forceinline__ f32x2 bfpair(u32 u) {
  f32x2 r;
  r.x = __uint_as_float(u << 16);
  r.y = __uint_as_float(u & 0xFFFF0000u);
  return r;
}

// Rearrange W[h][k][d] (f32) into bf16 MFMA B-fragment order:
// Wb[(((pj*8+ct)*4+kc)*64+l)*8+b] = W_pj[c>>5][c&31][d],
//   c = ct*16 + (l&15),  d = kc*32 + (b>>2)*16 + ((l>>4)<<2) + (b&3)
__global__ void prep_weights(const float* __restrict__ Wk,
                             const float* __restrict__ Ws,
                             const float* __restrict__ Wv,
                             u16* __restrict__ Wb) {
  int idx = blockIdx.x * 256 + threadIdx.x;
  if (idx >= 3 * 8 * 4 * 64 * 8) return;
  int b  = idx & 7;
  int l  = (idx >> 3) & 63;
  int kc = (idx >> 9) & 3;
  int ct = (idx >> 11) & 7;
  int pj = idx >> 14;
  int c = ct * 16 + (l & 15);
  int h = c >> 5, kk = c & 31;
  int d = kc * 32 + ((b >> 2) << 4) + ((l >> 4) << 2) + (b & 3);
  const float* W = (pj == 0) ? Wk : ((pj == 1) ? Ws : Wv);
  Wb[idx] = f2bf(W[(h * KDIM + kk) * DDIM + d]);
}

__global__ __launch_bounds__(256, 6) void fused_attn(
    const float* __restrict__ qin, const float* __restrict__ kin,
    const float* __restrict__ vin, const u16* __restrict__ Wb,
    const float* __restrict__ bv,
    float* __restrict__ out0, float* __restrict__ out1,
    float* __restrict__ out2) {
  // hk / hs / hv as bf16 [32 rows][128 cols], XOR-swizzled:
  // elem(row,c) at byte row*256 + ((c*2) ^ ((row&7)<<4)).  24 KB total.
  __shared__ __align__(16) u16 sH[3][MROWS * CC];

  const int tid = threadIdx.x;
  const int l = tid & 63;
  const int w = tid >> 6;
  const int n0 = blockIdx.x * NT;
  const int lr = l & 15;
  const int lg = l >> 4;
  const int wr = w >> 1;  // row-half of the 2x2 wave grid
  const int wc = w & 1;   // col-half

  // ---- projection phase: wave (wr,wc) owns rows [16wr,16wr+16) x cols [64wc,64wc+64) ----
  const int arow = wr * 16 + lr;  // local row = agent*4 + nt
  const size_t grow_off =
      ((size_t)(arow >> 2) * NBATCH + (size_t)(n0 + (arow & 3))) * DDIM;

#pragma unroll
  for (int pj = 0; pj < 3; ++pj) {
    const float* X = (pj == 0) ? kin : ((pj == 1) ? qin : vin);
    const float* grow = X + grow_off;

    FragU fa[4];
#pragma unroll
    for (int kc = 0; kc < 4; ++kc) {
      const float4 x0 = *(const float4*)(grow + kc * 32 + lg * 4);
      const float4 x1 = *(const float4*)(grow + kc * 32 + lg * 4 + 16);
      u32x4 t;
      t[0] = cvtpk(x0.x, x0.y);
      t[1] = cvtpk(x0.z, x0.w);
      t[2] = cvtpk(x1.x, x1.y);
      t[3] = cvtpk(x1.z, x1.w);
      fa[kc].u = t;
    }

    f32x4 acc[4];
#pragma unroll
    for (int ct = 0; ct < 4; ++ct) acc[ct] = (f32x4)(0.0f);

#pragma unroll
    for (int ct = 0; ct < 4; ++ct) {
      const int ctg = wc * 4 + ct;
#pragma unroll
      for (int kc = 0; kc < 4; ++kc) {
        FragU fb;
        fb.s = *(const s16x8*)(Wb + ((((pj * 8 + ctg) * 4 + kc) * 64 + l) << 3));
        acc[ct] = __builtin_amdgcn_mfma_f32_16x16x32_bf16(fa[kc].b, fb.b,
                                                          acc[ct], 0, 0, 0);
      }
    }

    // epilogue: D-frag lane l holds col=ctg*16+lr, rows 16wr + lg*4 + rg
    u16* dst = sH[pj];
#pragma unroll
    for (int ct = 0; ct < 4; ++ct) {
      const int c = (wc * 4 + ct) * 16 + lr;
      float x[4];
#pragma unroll
      for (int rg = 0; rg < 4; ++rg) x[rg] = acc[ct][rg];
      if (pj == 2) {
        const float bias = bv[c];
#pragma unroll
        for (int rg = 0; rg < 4; ++rg) {
          float v = x[rg] + bias;
          x[rg] = (v > 0.0f) ? v : 0.01f * v;
        }
      }
      const u32 p01 = cvtpk(x[0], x[1]);
      const u32 p23 = cvtpk(x[2], x[3]);
      const int rb = wr * 16 + lg * 4;
      const int cb = c * 2;
#pragma unroll
      for (int rg = 0; rg < 4; ++rg) {
        const int row = rb + rg;
        const u32 pk = (rg < 2) ? p01 : p23;
        const u16 val = (rg & 1) ? (u16)(pk >> 16) : (u16)pk;
        *(u16*)((char*)dst + row * 256 + (cb ^ ((row & 7) << 4))) = val;
      }
    }
  }

  __syncthreads();

  // ---- attention phase: thread = (h=wave, i=l>>3, nt=(l>>1)&3, half=l&1) ----
  // Each (h,i,nt) unit is split over 2 lanes; each lane handles 16 of the
  // 32 k-dims. Logit partials combined with one shfl_xor(1).
  const int h = w;
  const int i = l >> 3;
  const int nt = (l >> 1) & 3;
  const int half = l & 1;
  const int n = n0 + nt;
  const int cb = h * 64 + half * 32;  // byte offset of this lane's 16-col slice

  // own selector row slice, as 8 packed f32 pairs (16 cols)
  f32x2 hs2[8];
  {
    const int r = i * 4 + nt;
    const int swz = (r & 7) << 4;
#pragma unroll
    for (int qc = 0; qc < 2; ++qc) {
      u32x4 ch = *(const u32x4*)((const char*)sH[1] + r * 256 +
                                 ((cb + qc * 16) ^ swz));
#pragma unroll
      for (int e = 0; e < 4; ++e) hs2[qc * 4 + e] = bfpair(ch[e]);
    }
  }

  float logits[8];
#pragma unroll
  for (int j = 0; j < 8; ++j) {
    const int r = j * 4 + nt;
    const int swz = (r & 7) << 4;
    f32x2 a2 = (f32x2)(0.0f);
#pragma unroll
    for (int qc = 0; qc < 2; ++qc) {
      u32x4 ch = *(const u32x4*)((const char*)sH[0] + r * 256 +
                                 ((cb + qc * 16) ^ swz));
#pragma unroll
      for (int e = 0; e < 4; ++e) a2 = bfpair(ch[e]) * hs2[qc * 4 + e] + a2;
    }
    const float part = a2.x + a2.y;
    logits[j] = part + __shfl_xor(part, 1);
  }

  const float scale = 0.17677669529663687f;  // 1/sqrt(32)
  float sl[8];
#pragma unroll
  for (int j = 0; j < 8; ++j) sl[j] = (j == i) ? -1e30f : logits[j] * scale;
  float m = sl[0];
#pragma unroll
  for (int j = 1; j < 8; ++j) m = fmaxf(m, sl[j]);
  float p[8];
  float s = 0.0f;
#pragma unroll
  for (int j = 0; j < 8; ++j) { p[j] = __expf(sl[j] - m); s += p[j]; }
  const float inv = 1.0f / s;

  const size_t ob = ((size_t)(i * HEADS + h) * NBATCH + (size_t)n);
  const size_t ob7 = ob * 7;
  if (half == 0) {
#pragma unroll
    for (int j = 0; j < 8; ++j) {
      if (j != i) {
        const int jj = j - ((j > i) ? 1 : 0);
        out1[ob7 + jj] = logits[j];  // UNSCALED logits (reference semantics)
      }
    }
  } else {
#pragma unroll
    for (int j = 0; j < 8; ++j) {
      if (j != i) {
        const int jj = j - ((j > i) ? 1 : 0);
        out2[ob7 + jj] = p[j] * inv;
      }
    }
  }

  // PV: this lane's 16 cols, packed f32x2 accumulate
  f32x2 o2[8];
#pragma unroll
  for (int e = 0; e < 8; ++e) o2[e] = (f32x2)(0.0f);
#pragma unroll
  for (int j = 0; j < 8; ++j) {
    const float pw = p[j] * inv;  // pw == 0 for j == i
    const f32x2 pw2 = (f32x2)(pw);
    const int r = j * 4 + nt;
    const int swz = (r & 7) << 4;
#pragma unroll
    for (int qc = 0; qc < 2; ++qc) {
      u32x4 ch = *(const u32x4*)((const char*)sH[2] + r * 256 +
                                 ((cb + qc * 16) ^ swz));
#pragma unroll
      for (int e = 0; e < 4; ++e)
        o2[qc * 4 + e] = bfpair(ch[e]) * pw2 + o2[qc * 4 + e];
    }
  }

  const size_t o0 = ob * 32 + half * 16;
#pragma unroll
  for (int g = 0; g < 4; ++g) {
    float4 vv = make_float4(o2[g * 2].x, o2[g * 2].y,
                            o2[g * 2 + 1].x, o2[g * 2 + 1].y);
    *(float4*)(out0 + o0 + g * 4) = vv;
  }
}

extern "C" void kernel_launch(void* const* d_in, const int* in_sizes, int n_in,
                              void* d_out, int out_size, void* d_ws,
                              size_t ws_size, hipStream_t stream) {
  const float* qin = (const float*)d_in[0];
  const float* kin = (const float*)d_in[1];
  const float* vin = (const float*)d_in[2];
  const float* Wk  = (const float*)d_in[3];
  const float* Ws  = (const float*)d_in[4];
  const float* Wv  = (const float*)d_in[5];
  const float* bvp = (const float*)d_in[6];

  float* out0 = (float*)d_out;
  float* out1 = out0 + (size_t)AGT * HEADS * NBATCH * KDIM;
  float* out2 = out1 + (size_t)AGT * HEADS * NBATCH * 7;

  u16* Wb = (u16*)d_ws;  // 98304 bytes needed

  prep_weights<<<dim3(192), dim3(256), 0, stream>>>(Wk, Ws, Wv, Wb);
  fused_attn<<<dim3(NBATCH / NT), dim3(256), 0, stream>>>(
      qin, kin, vin, Wb, bvp, out0, out1, out2);
}

// Round 5
// 272.041 us; speedup vs baseline: 1.0082x; 1.0043x over previous
//
#include <hip/hip_runtime.h>
#include <hip/hip_bf16.h>

typedef unsigned short u16;
typedef unsigned int u32;

#define AGT 8
#define NBATCH 32768
#define DDIM 128
#define HEADS 4
#define KDIM 32

typedef float f32x4 __attribute__((ext_vector_type(4)));
typedef __bf16 bf16x8 __attribute__((ext_vector_type(8)));
typedef short s16x8 __attribute__((ext_vector_type(8)));
typedef u32 u32x4 __attribute__((ext_vector_type(4)));

union FragU { s16x8 s; bf16x8 b; u32x4 u; };

__device__ __forceinline__ u16 f2bf(float f) {
  u32 u = __float_as_uint(f);
  u = (u + 0x7FFFu + ((u >> 16) & 1u)) >> 16;
  return (u16)u;
}

// compiler-visible packed f32->bf16 (no inline asm: keeps the GCN hazard
// recognizer in the loop between MFMA writes and these reads)
__device__ __forceinline__ u32 packbf(float lo, float hi) {
  return (u32)f2bf(lo) | ((u32)f2bf(hi) << 16);
}

// Rearrange W[h][k][d] (f32) into bf16 MFMA fragment order (A- or B-side,
// same map): Wb[(((pj*8+t)*4+kc)*64+l)*8+b] = W_pj[c>>5][c&31][d],
//   c = t*16 + (l&15),  d = kc*32 + (b>>2)*16 + ((l>>4)<<2) + (b&3)
__global__ void prep_weights(const float* __restrict__ Wk,
                             const float* __restrict__ Ws,
                             const float* __restrict__ Wv,
                             u16* __restrict__ Wb) {
  int idx = blockIdx.x * 256 + threadIdx.x;
  if (idx >= 3 * 8 * 4 * 64 * 8) return;
  int b  = idx & 7;
  int l  = (idx >> 3) & 63;
  int kc = (idx >> 9) & 3;
  int t  = (idx >> 11) & 7;
  int pj = idx >> 14;
  int c = t * 16 + (l & 15);
  int h = c >> 5, kk = c & 31;
  int d = kc * 32 + ((b >> 2) << 4) + ((l >> 4) << 2) + (b & 3);
  const float* W = (pj == 0) ? Wk : ((pj == 1) ? Ws : Wv);
  Wb[idx] = f2bf(W[(h * KDIM + kk) * DDIM + d]);
}

// Load one X row's fragment: lane holds row (l&15), d-slots per the Wb map.
__device__ __forceinline__ void load_pack_row(const float* __restrict__ rowp,
                                              int lg, FragU f[4]) {
#pragma unroll
  for (int kc = 0; kc < 4; ++kc) {
    const float4 x0 = *(const float4*)(rowp + kc * 32 + lg * 4);
    const float4 x1 = *(const float4*)(rowp + kc * 32 + lg * 4 + 16);
    u32x4 t;
    t[0] = packbf(x0.x, x0.y);
    t[1] = packbf(x0.z, x0.w);
    t[2] = packbf(x1.x, x1.y);
    t[3] = packbf(x1.z, x1.w);
    f[kc].u = t;
  }
}

__global__ __launch_bounds__(256, 2) void fused_attn(
    const float* __restrict__ qin, const float* __restrict__ kin,
    const float* __restrict__ vin, const u16* __restrict__ Wb,
    const float* __restrict__ bv,
    float* __restrict__ out0, float* __restrict__ out1,
    float* __restrict__ out2) {
  const int tid = threadIdx.x;
  const int l = tid & 63;
  const int w = tid >> 6;
  const int lr = l & 15;
  const int lg = l >> 4;
  // wave tile: 16 rows = 8 agents x 2 consecutive n
  const int n_base = blockIdx.x * 8 + w * 2;
  const int my_agent = lr >> 1;
  const int my_n = n_base + (lr & 1);
  const size_t xoff = ((size_t)my_agent * NBATCH + (size_t)my_n) * DDIM;

  const f32x4 zero4 = (f32x4)(0.0f);

  // ---- hk^T = Wk . X_k^T  (A = Wk frag, B = X frag) ----
  FragU hk4[HEADS];  // per head: A-frag of S-mfma (8 bf16)
  {
    FragU fx[4];
    load_pack_row(kin + xoff, lg, fx);
    f32x4 a[8];
#pragma unroll
    for (int mt = 0; mt < 8; ++mt) {
      a[mt] = zero4;
#pragma unroll
      for (int kc = 0; kc < 4; ++kc) {
        FragU fb;
        fb.s = *(const s16x8*)(Wb + ((((0 * 8 + mt) * 4 + kc) * 64 + l) << 3));
        a[mt] = __builtin_amdgcn_mfma_f32_16x16x32_bf16(fb.b, fx[kc].b, a[mt],
                                                        0, 0, 0);
      }
    }
#pragma unroll
    for (int h = 0; h < HEADS; ++h) {
      u32x4 t;
      t[0] = packbf(a[2 * h][0], a[2 * h][1]);
      t[1] = packbf(a[2 * h][2], a[2 * h][3]);
      t[2] = packbf(a[2 * h + 1][0], a[2 * h + 1][1]);
      t[3] = packbf(a[2 * h + 1][2], a[2 * h + 1][3]);
      hk4[h].u = t;
    }
  }

  // ---- hs^T = Wsel . X_q^T ----
  FragU hs4[HEADS];
  {
    FragU fx[4];
    load_pack_row(qin + xoff, lg, fx);
    f32x4 a[8];
#pragma unroll
    for (int mt = 0; mt < 8; ++mt) {
      a[mt] = zero4;
#pragma unroll
      for (int kc = 0; kc < 4; ++kc) {
        FragU fb;
        fb.s = *(const s16x8*)(Wb + ((((1 * 8 + mt) * 4 + kc) * 64 + l) << 3));
        a[mt] = __builtin_amdgcn_mfma_f32_16x16x32_bf16(fb.b, fx[kc].b, a[mt],
                                                        0, 0, 0);
      }
    }
#pragma unroll
    for (int h = 0; h < HEADS; ++h) {
      u32x4 t;
      t[0] = packbf(a[2 * h][0], a[2 * h][1]);
      t[1] = packbf(a[2 * h][2], a[2 * h][3]);
      t[2] = packbf(a[2 * h + 1][0], a[2 * h + 1][1]);
      t[3] = packbf(a[2 * h + 1][2], a[2 * h + 1][3]);
      hs4[h].u = t;
    }
  }

  // ---- hv = X_v . Wv^T (normal orientation; A = X frag, B = Wv frag) ----
  // hv4[ct] = B-frag (j rows in k-slots 0..15, zero-padded 16..31) for
  // PV tile ct = 2h + d-half.
  FragU hv4[8];
  {
    FragU fx[4];
    load_pack_row(vin + xoff, lg, fx);
#pragma unroll
    for (int ct = 0; ct < 8; ++ct) {
      f32x4 a = zero4;
#pragma unroll
      for (int kc = 0; kc < 4; ++kc) {
        FragU fb;
        fb.s = *(const s16x8*)(Wb + ((((2 * 8 + ct) * 4 + kc) * 64 + l) << 3));
        a = __builtin_amdgcn_mfma_f32_16x16x32_bf16(fx[kc].b, fb.b, a, 0, 0, 0);
      }
      const float bias = bv[ct * 16 + lr];
      float x[4];
#pragma unroll
      for (int rg = 0; rg < 4; ++rg) {
        float v = a[rg] + bias;
        x[rg] = (v > 0.0f) ? v : 0.01f * v;
      }
      u32x4 t;
      t[0] = packbf(x[0], x[1]);
      t[1] = packbf(x[2], x[3]);
      t[2] = 0;
      t[3] = 0;
      hv4[ct].u = t;
    }
  }

  // ---- attention, fully in-register; per head:
  // S^T = mfma(hk, hs): lane holds S^T(j=4*lg+rg, i=lr), valid iff
  // parity(j)==parity(i) (same n) ----
  const float scale = 0.17677669529663687f;  // 1/sqrt(32)
  const int ipar = lr & 1;

#pragma unroll
  for (int h = 0; h < HEADS; ++h) {
    f32x4 S = __builtin_amdgcn_mfma_f32_16x16x32_bf16(hk4[h].b, hs4[h].b,
                                                      zero4, 0, 0, 0);
    float sl[4];
#pragma unroll
    for (int rg = 0; rg < 4; ++rg) {
      const int jrow = 4 * lg + rg;
      const bool valid = ((rg & 1) == ipar) && (jrow != lr);
      sl[rg] = valid ? S[rg] * scale : -1e30f;
    }
    float mp = fmaxf(fmaxf(sl[0], sl[1]), fmaxf(sl[2], sl[3]));
    mp = fmaxf(mp, __shfl_xor(mp, 16));
    mp = fmaxf(mp, __shfl_xor(mp, 32));
    float e[4];
    float sp = 0.0f;
#pragma unroll
    for (int rg = 0; rg < 4; ++rg) {
      e[rg] = __expf(sl[rg] - mp);  // invalid -> exp(-huge) == 0
      sp += e[rg];
    }
    sp += __shfl_xor(sp, 16);
    sp += __shfl_xor(sp, 32);
    const float inv = 1.0f / sp;
    float p[4];
#pragma unroll
    for (int rg = 0; rg < 4; ++rg) p[rg] = e[rg] * inv;

    // out1 (raw logits) / out2 (probs): writer = lane holding that j
    const int a_i = lr >> 1;
    const int n = n_base + ipar;
    const size_t ob7 = ((size_t)(a_i * HEADS + h) * NBATCH + (size_t)n) * 7;
#pragma unroll
    for (int rg = 0; rg < 4; ++rg) {
      const int jrow = 4 * lg + rg;
      if (((rg & 1) == ipar) && (jrow != lr)) {
        const int a_j = jrow >> 1;
        const int jj = a_j - ((a_j > a_i) ? 1 : 0);
        out1[ob7 + jj] = S[rg];
        out2[ob7 + jj] = p[rg];
      }
    }

    // PV: O = P(16x16, zero-masked) . hv ; K zero-padded to 32
    FragU P;
    {
      u32x4 t;
      t[0] = packbf(p[0], p[1]);
      t[1] = packbf(p[2], p[3]);
      t[2] = 0;
      t[3] = 0;
      P.u = t;
    }
    f32x4 O0 = __builtin_amdgcn_mfma_f32_16x16x32_bf16(P.b, hv4[2 * h].b,
                                                       zero4, 0, 0, 0);
    f32x4 O1 = __builtin_amdgcn_mfma_f32_16x16x32_bf16(P.b, hv4[2 * h + 1].b,
                                                       zero4, 0, 0, 0);
    // lane holds O(i_row=4*lg+rg, d = half*16 + lr)
#pragma unroll
    for (int rg = 0; rg < 4; ++rg) {
      const int irow = 4 * lg + rg;
      const int a_o = irow >> 1;
      const int n_o = n_base + (irow & 1);
      const size_t o0 =
          ((size_t)(a_o * HEADS + h) * NBATCH + (size_t)n_o) * KDIM;
      out0[o0 + lr] = O0[rg];
      out0[o0 + 16 + lr] = O1[rg];
    }
  }
}

extern "C" void kernel_launch(void* const* d_in, const int* in_sizes, int n_in,
                              void* d_out, int out_size, void* d_ws,
                              size_t ws_size, hipStream_t stream) {
  const float* qin = (const float*)d_in[0];
  const float* kin = (const float*)d_in[1];
  const float* vin = (const float*)d_in[2];
  const float* Wk  = (const float*)d_in[3];
  const float* Ws  = (const float*)d_in[4];
  const float* Wv  = (const float*)d_in[5];
  const float* bvp = (const float*)d_in[6];

  float* out0 = (float*)d_out;
  float* out1 = out0 + (size_t)AGT * HEADS * NBATCH * KDIM;
  float* out2 = out1 + (size_t)AGT * HEADS * NBATCH * 7;

  u16* Wb = (u16*)d_ws;  // 98304 bytes needed

  prep_weights<<<dim3(192), dim3(256), 0, stream>>>(Wk, Ws, Wv, Wb);
  // 4 waves/block, each wave = 8 agents x 2 n, fully independent (no LDS)
  fused_attn<<<dim3(NBATCH / 8), dim3(256), 0, stream>>>(
      qin, kin, vin, Wb, bvp, out0, out1, out2);
}